// Round 1
// baseline (454.509 us; speedup 1.0000x reference)
//
#include <hip/hip_runtime.h>
#include <math.h>

#define NUM_CLASSES 80
#define FLOAT4_PER_ROW (NUM_CLASSES / 4)   // 20

constexpr float ALPHA = 0.25f;
constexpr float CENTER_W = 0.1f;
constexpr float EPS_GIOU = 1e-7f;

// ---------------------------------------------------------------------------
// Kernel 1: per-row losses, block-reduced into double partials (3 per block)
// ---------------------------------------------------------------------------
__global__ __launch_bounds__(256) void hdm_loss_kernel(
    const float* __restrict__ cls_logits,   // (N, 80)
    const float* __restrict__ bbox_reg,     // (N, 4)
    const float* __restrict__ centerness,   // (N,)
    const float* __restrict__ gt_bboxes,    // (N, 4)
    const int*   __restrict__ gt_classes,   // (N,)
    double* __restrict__ partials,          // (gridDim.x, 3)
    int n)
{
    const int row = blockIdx.x * blockDim.x + threadIdx.x;

    float focal_t = 0.0f, giou_t = 0.0f, center_t = 0.0f;

    if (row < n) {
        // ---------------- focal loss ----------------
        const float4* lp = (const float4*)(cls_logits + (size_t)row * NUM_CLASSES);
        float4 v[FLOAT4_PER_ROW];
        #pragma unroll
        for (int j = 0; j < FLOAT4_PER_ROW; ++j) v[j] = lp[j];

        float m = -INFINITY;
        #pragma unroll
        for (int j = 0; j < FLOAT4_PER_ROW; ++j) {
            m = fmaxf(m, fmaxf(fmaxf(v[j].x, v[j].y), fmaxf(v[j].z, v[j].w)));
        }
        float s = 0.0f;
        #pragma unroll
        for (int j = 0; j < FLOAT4_PER_ROW; ++j) {
            s += __expf(v[j].x - m);
            s += __expf(v[j].y - m);
            s += __expf(v[j].z - m);
            s += __expf(v[j].w - m);
        }
        const int gc = gt_classes[row];
        // dynamic register indexing would spill; re-read from global (hot in L1/L2)
        const float xg = cls_logits[(size_t)row * NUM_CLASSES + gc];
        const float lse = m + __logf(s);
        const float ce  = lse - xg;
        const float pt  = __expf(-ce);
        const float omp = 1.0f - pt;
        focal_t = ALPHA * omp * omp * ce;

        // ---------------- GIoU loss ----------------
        const float4 p = ((const float4*)bbox_reg)[row];
        const float4 g = ((const float4*)gt_bboxes)[row];
        const float iw = fmaxf(fminf(p.z, g.z) - fmaxf(p.x, g.x), 0.0f);
        const float ih = fmaxf(fminf(p.w, g.w) - fmaxf(p.y, g.y), 0.0f);
        const float inter  = iw * ih;
        const float area_p = (p.z - p.x) * (p.w - p.y);
        const float area_g = (g.z - g.x) * (g.w - g.y);
        const float uni    = area_p + area_g - inter;
        const float iou    = inter / (uni + EPS_GIOU);
        const float cw = fmaxf(p.z, g.z) - fminf(p.x, g.x);
        const float ch = fmaxf(p.w, g.w) - fminf(p.y, g.y);
        const float area_c = cw * ch;
        const float giou = iou - (area_c - uni) / (area_c + EPS_GIOU);
        giou_t = 1.0f - giou;

        // ---------------- centerness loss: softplus(-c) ----------------
        const float c = centerness[row];
        center_t = fmaxf(-c, 0.0f) + log1pf(__expf(-fabsf(c)));
    }

    // ---------------- block reduction (double) ----------------
    double f = (double)focal_t, gi = (double)giou_t, ce_ = (double)center_t;
    #pragma unroll
    for (int off = 32; off > 0; off >>= 1) {
        f   += __shfl_down(f,   off, 64);
        gi  += __shfl_down(gi,  off, 64);
        ce_ += __shfl_down(ce_, off, 64);
    }
    __shared__ double sf[4], sg[4], sc[4];
    const int lane = threadIdx.x & 63;
    const int wave = threadIdx.x >> 6;
    if (lane == 0) { sf[wave] = f; sg[wave] = gi; sc[wave] = ce_; }
    __syncthreads();
    if (threadIdx.x == 0) {
        double tf = 0.0, tg = 0.0, tc = 0.0;
        #pragma unroll
        for (int w = 0; w < 4; ++w) { tf += sf[w]; tg += sg[w]; tc += sc[w]; }
        partials[blockIdx.x * 3 + 0] = tf;
        partials[blockIdx.x * 3 + 1] = tg;
        partials[blockIdx.x * 3 + 2] = tc;
    }
}

// ---------------------------------------------------------------------------
// Kernel 2: reduce partials, write the 4 output scalars
// ---------------------------------------------------------------------------
__global__ __launch_bounds__(256) void hdm_finalize_kernel(
    const double* __restrict__ partials, int nblocks, int n,
    float* __restrict__ out)
{
    double f = 0.0, g = 0.0, c = 0.0;
    for (int i = threadIdx.x; i < nblocks; i += 256) {
        f += partials[i * 3 + 0];
        g += partials[i * 3 + 1];
        c += partials[i * 3 + 2];
    }
    #pragma unroll
    for (int off = 32; off > 0; off >>= 1) {
        f += __shfl_down(f, off, 64);
        g += __shfl_down(g, off, 64);
        c += __shfl_down(c, off, 64);
    }
    __shared__ double sf[4], sg[4], sc[4];
    const int lane = threadIdx.x & 63;
    const int wave = threadIdx.x >> 6;
    if (lane == 0) { sf[wave] = f; sg[wave] = g; sc[wave] = c; }
    __syncthreads();
    if (threadIdx.x == 0) {
        double tf = 0.0, tg = 0.0, tc = 0.0;
        #pragma unroll
        for (int w = 0; w < 4; ++w) { tf += sf[w]; tg += sg[w]; tc += sc[w]; }
        const double inv_n = 1.0 / (double)n;
        const double focal_mean  = tf * inv_n;
        const double iou_mean    = tg * inv_n;
        const double center_mean = tc * inv_n;
        const double total = focal_mean + iou_mean + (double)CENTER_W * center_mean;
        out[0] = (float)total;
        out[1] = (float)focal_mean;
        out[2] = (float)iou_mean;
        out[3] = (float)center_mean;
    }
}

extern "C" void kernel_launch(void* const* d_in, const int* in_sizes, int n_in,
                              void* d_out, int out_size, void* d_ws, size_t ws_size,
                              hipStream_t stream) {
    const float* cls_logits = (const float*)d_in[0];
    const float* bbox_reg   = (const float*)d_in[1];
    const float* centerness = (const float*)d_in[2];
    const float* gt_bboxes  = (const float*)d_in[3];
    const int*   gt_classes = (const int*)d_in[4];
    float* out = (float*)d_out;

    const int n = in_sizes[2];              // centerness element count == N
    const int nblocks = (n + 255) / 256;    // 3907 for N=1e6
    double* partials = (double*)d_ws;       // nblocks*3*8B ≈ 94 KB

    hdm_loss_kernel<<<nblocks, 256, 0, stream>>>(
        cls_logits, bbox_reg, centerness, gt_bboxes, gt_classes, partials, n);
    hdm_finalize_kernel<<<1, 256, 0, stream>>>(partials, nblocks, n, out);
}